// Round 16
// baseline (89.007 us; speedup 1.0000x reference)
//
#include <hip/hip_runtime.h>
#include <hip/hip_bf16.h>

typedef __bf16 bf16_8 __attribute__((ext_vector_type(8)));
typedef _Float16 f16x8 __attribute__((ext_vector_type(8)));
typedef float f32x4 __attribute__((ext_vector_type(4)));
typedef float f32x16 __attribute__((ext_vector_type(16)));

#define MFMA_BF(A, B, C)    __builtin_amdgcn_mfma_f32_16x16x32_bf16(A, B, C, 0, 0, 0)
#define MFMA_F16(A, B, C)   __builtin_amdgcn_mfma_f32_16x16x32_f16(A, B, C, 0, 0, 0)
#define MFMA32_F16(A, B, C) __builtin_amdgcn_mfma_f32_32x32x16_f16(A, B, C, 0, 0, 0)
#define MFMA32_BF(A, B, C)  __builtin_amdgcn_mfma_f32_32x32x16_bf16(A, B, C, 0, 0, 0)

#define BATCH 8
#define NPOS 4096            // 64*64 spatial
#define CIN 256
#define CMID 64
#define OC 256
#define NROWS (BATCH * NPOS) // 32768
#define NSPLIT 4             // j-split (nsplit=8 regressed: reg cap is 16 waves/CU)
#define LOG2E 1.44269504088896f

// lane i <-> lane i+32 register swap (hi half of a <-> lo half of b)
__device__ inline void swaplane32(unsigned& a, unsigned& b) {
    asm volatile("v_permlane32_swap_b32 %0, %1" : "+v"(a), "+v"(b));
}

// single-instruction 2^x. R11 LESSON: bare inline-asm v_exp_f32 is WRONG —
// trans-op forwarding hazard invisible to the compiler. Builtin is safe.
#if __has_builtin(__builtin_amdgcn_exp2f)
__device__ inline float fexp2(float x) { return __builtin_amdgcn_exp2f(x); }
#else
__device__ inline float fexp2(float x) {
    float r;
    asm("v_exp_f32 %0, %1\n\ts_nop 1" : "=v"(r) : "v"(x));  // nop INSIDE blob
    return r;
}
#endif

// ---------------------------------------------------------------------------
// wprep_kernel: WoT[col][k] = bf16(Wo[k][col] * sc[col]) with BN scale
// folded; sh_ws[col] = beta - mmean*sc. 16384 elems, grid 64.
// ---------------------------------------------------------------------------
__global__ __launch_bounds__(256) void wprep_kernel(
    const float* __restrict__ Wo,
    const float* __restrict__ gamma, const float* __restrict__ beta,
    const float* __restrict__ mmean, const float* __restrict__ mvar,
    __bf16* __restrict__ WoT, float* __restrict__ sh_ws)
{
    int idx = blockIdx.x * 256 + threadIdx.x;   // 0..16383
    int col = idx >> 6, k = idx & 63;
    float sc = gamma[col] * rsqrtf(mvar[col] + 1e-3f);
    WoT[col * 64 + k] = (__bf16)(Wo[k * OC + col] * sc);
    if (k == 0) sh_ws[col] = beta[col] - mmean[col] * sc;
}

// ---------------------------------------------------------------------------
// proj_kernel (R12 structure): one of {k,q,v} = x @ W, all-fp16 inputs.
// Wk pre-scaled by log2e so flash uses exp2 directly. grid (512, 3).
// R16: W staging vectorized float4 (64 scalar loads -> 16 float4 loads per
// thread; wave covers 1KB contiguous; LDS write lands 2-way = free).
// R14 LESSON: W-fragments straight from global regressed — keep LDS staging.
// ---------------------------------------------------------------------------
__global__ __launch_bounds__(256) void proj_kernel(
    const float* __restrict__ x,
    const float* __restrict__ Wk, const float* __restrict__ Wq,
    const float* __restrict__ Wv,
    _Float16* __restrict__ k_ws, _Float16* __restrict__ q_ws,
    __bf16* __restrict__ vT_ws)
{
    const int m = blockIdx.y;
    const int r0 = blockIdx.x * 64;
    const float* W = (m == 0) ? Wk : (m == 1) ? Wq : Wv;
    const float wscale = (m == 0) ? LOG2E : 1.0f;

    __shared__ _Float16 wt[64][266];   // W^T [col][k]

    for (int idx = threadIdx.x; idx < 64 * 64; idx += 256) {
        int c4 = (idx & 15) * 4, k = idx >> 4;
        float4 w4 = *(const float4*)&W[k * 64 + c4];
        wt[c4 + 0][k] = (_Float16)(w4.x * wscale);
        wt[c4 + 1][k] = (_Float16)(w4.y * wscale);
        wt[c4 + 2][k] = (_Float16)(w4.z * wscale);
        wt[c4 + 3][k] = (_Float16)(w4.w * wscale);
    }

    const int lane = threadIdx.x & 63;
    const int wv = threadIdx.x >> 6;
    const int kbase = ((lane >> 4) & 3) * 8;
    const int arow = r0 + wv * 16 + (lane & 15);
    const float* xrow = x + (size_t)arow * CIN;

    f16x8 a[8];
    #pragma unroll
    for (int kk = 0; kk < 8; ++kk) {
        const float4* xp = (const float4*)(xrow + kk * 32 + kbase);
        float4 x0 = xp[0], x1 = xp[1];
        float xs[8] = {x0.x, x0.y, x0.z, x0.w, x1.x, x1.y, x1.z, x1.w};
        #pragma unroll
        for (int e = 0; e < 8; ++e) a[kk][e] = (_Float16)xs[e];
    }
    __syncthreads();

    f32x4 acc[4] = {f32x4{0,0,0,0}, f32x4{0,0,0,0}, f32x4{0,0,0,0}, f32x4{0,0,0,0}};
    #pragma unroll
    for (int kk = 0; kk < 8; ++kk) {
        #pragma unroll
        for (int nt = 0; nt < 4; ++nt) {
            f16x8 b = *(const f16x8*)&wt[(lane & 15) + 16 * nt][kk * 32 + kbase];
            acc[nt] = MFMA_F16(a[kk], b, acc[nt]);
        }
    }

    const int rloc = wv * 16 + ((lane >> 4) & 3) * 4;
    if (m < 2) {
        __syncthreads();
        _Float16* rp = &wt[0][0];          // viewed as [64][72]
        #pragma unroll
        for (int nt = 0; nt < 4; ++nt)
            #pragma unroll
            for (int r = 0; r < 4; ++r)
                rp[(rloc + r) * 72 + (lane & 15) + 16 * nt] = (_Float16)acc[nt][r];
        __syncthreads();
        _Float16* dst = (m == 0) ? k_ws : q_ws;
        const int row = threadIdx.x >> 3, c0 = (threadIdx.x & 7) * 8;
        #pragma unroll
        for (int h = 0; h < 2; ++h) {
            uint4 v = *(const uint4*)&rp[(row + 32 * h) * 72 + c0];
            *(uint4*)(dst + (size_t)(r0 + row + 32 * h) * CMID + c0) = v;
        }
    } else {
        const int rrow = r0 + rloc;
        const int b = rrow >> 12;
        const int n = rrow & (NPOS - 1);
        #pragma unroll
        for (int nt = 0; nt < 4; ++nt) {
            int cv = (lane & 15) + 16 * nt;
            union { __bf16 h[4]; uint2 u; } pk;
            #pragma unroll
            for (int r = 0; r < 4; ++r) pk.h[r] = (__bf16)acc[nt][r];
            *(uint2*)(vT_ws + ((size_t)b * CMID + cv) * NPOS + n) = pk.u;
        }
    }
}

// ---------------------------------------------------------------------------
// flash_kernel: EXACT R12 structure (proven 45.9 us). Streaming attention,
// 32x32 swapped-QK^T, in-register P, 8 waves x 32 i-rows (block=512),
// double-buffered tiles, issue-early/write-late staging, VALU den.
// (den-MFMA, setprio, nsplit=8, i=64/wave all regressed — R7/R10/R13.)
// grid (16, 8, NSPLIT).
// ---------------------------------------------------------------------------
__global__ __launch_bounds__(512, 4) void flash_kernel(
    const _Float16* __restrict__ k_ws,  // [32768][64]
    const _Float16* __restrict__ q_ws,  // [32768][64]
    const __bf16* __restrict__ vT_ws,   // [8][64][4096]
    __bf16* __restrict__ po,            // [NSPLIT][32768][64]
    float* __restrict__ pden)           // [NSPLIT][32768]
{
    const int b = blockIdx.y;
    const int i0 = blockIdx.x * 256;
    const int sblk = blockIdx.z;
    const int jbase = sblk * (NPOS / NSPLIT);
    const int lane = threadIdx.x & 63;
    const int wv = threadIdx.x >> 6;    // 0..7
    const int l31 = lane & 31;
    const int g = lane >> 5;

    __shared__ _Float16 qt[2][64][72];
    __shared__ __bf16 vt[2][64][72];

    // wave's 32 k-rows as B-fragments
    f16x8 kf[4];
    {
        const _Float16* kp =
            k_ws + ((size_t)(b * NPOS + i0 + wv * 32 + l31)) * CMID + g * 8;
        #pragma unroll
        for (int c = 0; c < 4; ++c) kf[c] = *(const f16x8*)(kp + c * 16);
    }

    f32x16 o0 = {0,0,0,0,0,0,0,0,0,0,0,0,0,0,0,0};
    f32x16 o1 = {0,0,0,0,0,0,0,0,0,0,0,0,0,0,0,0};
    float den = 0.f;

    // staging map: 512 threads x 16B = one 64x64 fp16/bf16 tile
    const int r = threadIdx.x >> 3, c0 = (threadIdx.x & 7) * 8;
    uint4 nq, nv;

    // prologue: tile 0
    {
        nq = *(const uint4*)(q_ws + ((size_t)(b * NPOS + jbase + r)) * CMID + c0);
        nv = *(const uint4*)(vT_ws + ((size_t)b * CMID + r) * NPOS + jbase + c0);
        *(uint4*)&qt[0][r][c0] = nq;
        *(uint4*)&vt[0][r][c0] = nv;
    }
    __syncthreads();

    const int NT = (NPOS / NSPLIT) / 64;  // 16
    for (int t = 0; t < NT; ++t) {
        const int cur = t & 1;
        if (t + 1 < NT) {   // issue next-tile loads early
            int j1 = jbase + (t + 1) * 64;
            nq = *(const uint4*)(q_ws + ((size_t)(b * NPOS + j1 + r)) * CMID + c0);
            nv = *(const uint4*)(vT_ws + ((size_t)b * CMID + r) * NPOS + j1 + c0);
        }

        #pragma unroll
        for (int jj = 0; jj < 2; ++jj) {
            f16x8 aq[4];
            #pragma unroll
            for (int c = 0; c < 4; ++c)
                aq[c] = *(const f16x8*)&qt[cur][jj * 32 + l31][c * 16 + g * 8];
            bf16_8 bv00 = *(const bf16_8*)&vt[cur][l31][jj * 32 + g * 8];
            bf16_8 bv01 = *(const bf16_8*)&vt[cur][l31][jj * 32 + 16 + g * 8];
            bf16_8 bv10 = *(const bf16_8*)&vt[cur][32 + l31][jj * 32 + g * 8];
            bf16_8 bv11 = *(const bf16_8*)&vt[cur][32 + l31][jj * 32 + 16 + g * 8];

            f32x16 s = {0,0,0,0,0,0,0,0,0,0,0,0,0,0,0,0};
            s = MFMA32_F16(aq[0], kf[0], s);
            s = MFMA32_F16(aq[1], kf[1], s);
            s = MFMA32_F16(aq[2], kf[2], s);
            s = MFMA32_F16(aq[3], kf[3], s);

            unsigned pk[8];
            #pragma unroll
            for (int m = 0; m < 8; ++m) {
                float p0 = fexp2(s[2 * m]);
                float p1 = fexp2(s[2 * m + 1]);
                den += p0 + p1;
                union { __bf16 h[2]; unsigned u; } w;
                w.h[0] = (__bf16)p0; w.h[1] = (__bf16)p1;
                pk[m] = w.u;
            }
            swaplane32(pk[0], pk[2]); swaplane32(pk[1], pk[3]);
            swaplane32(pk[4], pk[6]); swaplane32(pk[5], pk[7]);
            union { unsigned u[4]; bf16_8 v; } pa0, pa1;
            pa0.u[0] = pk[0]; pa0.u[1] = pk[1]; pa0.u[2] = pk[2]; pa0.u[3] = pk[3];
            pa1.u[0] = pk[4]; pa1.u[1] = pk[5]; pa1.u[2] = pk[6]; pa1.u[3] = pk[7];

            o0 = MFMA32_BF(pa0.v, bv00, o0);
            o0 = MFMA32_BF(pa1.v, bv01, o0);
            o1 = MFMA32_BF(pa0.v, bv10, o1);
            o1 = MFMA32_BF(pa1.v, bv11, o1);
        }

        if (t + 1 < NT) {   // write-late into the other buffer
            const int nb = cur ^ 1;
            *(uint4*)&qt[nb][r][c0] = nq;
            *(uint4*)&vt[nb][r][c0] = nv;
        }
        __syncthreads();
    }

    den += __shfl_xor(den, 32);

    const size_t rowb = (size_t)b * NPOS + i0 + wv * 32;
    if (lane < 32)
        pden[(size_t)sblk * NROWS + rowb + lane] = den;

    #pragma unroll
    for (int reg = 0; reg < 16; ++reg) {
        int il = (reg & 3) + 8 * (reg >> 2) + 4 * g;
        size_t base = ((size_t)sblk * NROWS + rowb + il) * CMID + l31;
        po[base]      = (__bf16)o0[reg];
        po[base + 32] = (__bf16)o1[reg];
    }
}

// ---------------------------------------------------------------------------
// out_kernel v3: 64 rows/block (grid 512). Wo fragments now 16B loads from
// pre-transposed WoT (BN scale folded; wprep) — replaces 64 scalar f32
// loads/thread. Combine j-split partials (uint2-vectorized) -> at bf16 ->
// rowgroup-looped MFMA -> +sh -> direct stores. block 256.
// ---------------------------------------------------------------------------
__global__ __launch_bounds__(256) void out_kernel(
    const __bf16* __restrict__ po,      // [NSPLIT][32768][64]
    const float* __restrict__ pden,     // [NSPLIT][32768]
    const __bf16* __restrict__ WoT,     // [256][64]  (Wo^T * sc, bf16)
    const float* __restrict__ sh_ws,    // [256]
    float* __restrict__ out)            // [32768][256]
{
    const int r0 = blockIdx.x * 64;
    const int t = threadIdx.x;
    const int lane = t & 63;
    const int wv = t >> 6;
    const int n0 = wv * 64;

    __shared__ __bf16 at[64][72];
    __shared__ float dinv[64];

    // Wo B-fragments: contiguous 16B loads from WoT (L2-hot)
    bf16_8 wb[4][2];
    float shs[4];
    #pragma unroll
    for (int nt = 0; nt < 4; ++nt) {
        int col = n0 + nt * 16 + (lane & 15);
        #pragma unroll
        for (int ch = 0; ch < 2; ++ch)
            wb[nt][ch] = *(const bf16_8*)&WoT[col * 64 + ch * 32 + (lane >> 4) * 8];
        shs[nt] = sh_ws[col];
    }

    if (t < 64) {
        float d = 0.f;
        #pragma unroll
        for (int s = 0; s < NSPLIT; ++s) d += pden[(size_t)s * NROWS + r0 + t];
        dinv[t] = 1.0f / d;
    }
    __syncthreads();

    // vectorized combine: 64x64 = 1024 quads, 4 per thread
    #pragma unroll
    for (int q = 0; q < 4; ++q) {
        int quad = t + q * 256;
        int rr = quad >> 4, c4 = (quad & 15) * 4;
        float s0 = 0.f, s1 = 0.f, s2 = 0.f, s3 = 0.f;
        #pragma unroll
        for (int s = 0; s < NSPLIT; ++s) {
            union { uint2 u; __bf16 h[4]; } qq;
            qq.u = *(const uint2*)&po[((size_t)s * NROWS + r0 + rr) * CMID + c4];
            s0 += (float)qq.h[0]; s1 += (float)qq.h[1];
            s2 += (float)qq.h[2]; s3 += (float)qq.h[3];
        }
        float di = dinv[rr];
        union { __bf16 h[4]; uint2 u; } o;
        o.h[0] = (__bf16)(s0 * di); o.h[1] = (__bf16)(s1 * di);
        o.h[2] = (__bf16)(s2 * di); o.h[3] = (__bf16)(s3 * di);
        *(uint2*)&at[rr][c4] = o.u;
    }
    __syncthreads();

    // rowgroup-looped MFMA: 4 groups of 16 rows
    #pragma unroll
    for (int rg = 0; rg < 4; ++rg) {
        bf16_8 a0 = *(const bf16_8*)&at[rg * 16 + (lane & 15)][(lane >> 4) * 8];
        bf16_8 a1 = *(const bf16_8*)&at[rg * 16 + (lane & 15)][32 + (lane >> 4) * 8];
        #pragma unroll
        for (int nt = 0; nt < 4; ++nt) {
            int col = n0 + nt * 16 + (lane & 15);
            f32x4 acc = {0.f, 0.f, 0.f, 0.f};
            acc = MFMA_BF(a0, wb[nt][0], acc);
            acc = MFMA_BF(a1, wb[nt][1], acc);
            int rl = rg * 16 + (lane >> 4) * 4;
            #pragma unroll
            for (int rr = 0; rr < 4; ++rr)
                out[(size_t)(r0 + rl + rr) * OC + col] = acc[rr] + shs[nt];
        }
    }
}

// ---------------------------------------------------------------------------
extern "C" void kernel_launch(void* const* d_in, const int* in_sizes, int n_in,
                              void* d_out, int out_size, void* d_ws, size_t ws_size,
                              hipStream_t stream) {
    const float* x     = (const float*)d_in[0];
    const float* Wk    = (const float*)d_in[1];
    const float* Wq    = (const float*)d_in[2];
    const float* Wv    = (const float*)d_in[3];
    const float* Wo    = (const float*)d_in[4];
    const float* gamma = (const float*)d_in[5];
    const float* beta  = (const float*)d_in[6];
    const float* mmean = (const float*)d_in[7];
    const float* mvar  = (const float*)d_in[8];
    float* out = (float*)d_out;

    // k/q/vT live in d_out (32 MiB): dead before out_kernel writes out.
    char* ob = (char*)d_out;
    const size_t MB4 = (size_t)NROWS * CMID * 2;   // 4 MiB
    _Float16* k_ws = (_Float16*)ob;                // 4 MiB
    _Float16* q_ws = (_Float16*)(ob + MB4);        // 4 MiB
    __bf16*   vT   = (__bf16*)(ob + 2 * MB4);      // 4 MiB

    // d_ws: po 16 MiB + pden 512 KiB + WoT 32 KiB + sh 1 KiB (ws >= 24 MiB)
    __bf16* po   = (__bf16*)d_ws;
    float*  pden = (float*)((char*)d_ws + (size_t)NSPLIT * MB4);
    __bf16* WoT  = (__bf16*)((char*)d_ws + (size_t)NSPLIT * MB4 + (size_t)NSPLIT * NROWS * 4);
    float*  shws = (float*)((char*)WoT + (size_t)OC * CMID * 2);

    wprep_kernel<<<64, 256, 0, stream>>>(Wo, gamma, beta, mmean, mvar, WoT, shws);
    proj_kernel<<<dim3(512, 3), 256, 0, stream>>>(x, Wk, Wq, Wv, k_ws, q_ws, vT);
    flash_kernel<<<dim3(16, 8, NSPLIT), 512, 0, stream>>>(k_ws, q_ws, vT, po, pden);
    out_kernel<<<512, 256, 0, stream>>>(po, pden, WoT, shws, out);
}

// Round 17
// 84.422 us; speedup vs baseline: 1.0543x; 1.0543x over previous
//
#include <hip/hip_runtime.h>
#include <hip/hip_bf16.h>

typedef __bf16 bf16_8 __attribute__((ext_vector_type(8)));
typedef _Float16 f16x8 __attribute__((ext_vector_type(8)));
typedef float f32x4 __attribute__((ext_vector_type(4)));
typedef float f32x16 __attribute__((ext_vector_type(16)));

#define MFMA_BF(A, B, C)    __builtin_amdgcn_mfma_f32_16x16x32_bf16(A, B, C, 0, 0, 0)
#define MFMA_F16(A, B, C)   __builtin_amdgcn_mfma_f32_16x16x32_f16(A, B, C, 0, 0, 0)
#define MFMA32_F16(A, B, C) __builtin_amdgcn_mfma_f32_32x32x16_f16(A, B, C, 0, 0, 0)
#define MFMA32_BF(A, B, C)  __builtin_amdgcn_mfma_f32_32x32x16_bf16(A, B, C, 0, 0, 0)

#define BATCH 8
#define NPOS 4096            // 64*64 spatial
#define CIN 256
#define CMID 64
#define OC 256
#define NROWS (BATCH * NPOS) // 32768
#define NSPLIT 4             // j-split (nsplit=8 regressed: reg cap is 16 waves/CU)
#define LOG2E 1.44269504088896f

// lane i <-> lane i+32 register swap (hi half of a <-> lo half of b)
__device__ inline void swaplane32(unsigned& a, unsigned& b) {
    asm volatile("v_permlane32_swap_b32 %0, %1" : "+v"(a), "+v"(b));
}

// single-instruction 2^x. R11 LESSON: bare inline-asm v_exp_f32 is WRONG —
// trans-op forwarding hazard invisible to the compiler. Builtin is safe.
#if __has_builtin(__builtin_amdgcn_exp2f)
__device__ inline float fexp2(float x) { return __builtin_amdgcn_exp2f(x); }
#else
__device__ inline float fexp2(float x) {
    float r;
    asm("v_exp_f32 %0, %1\n\ts_nop 1" : "=v"(r) : "v"(x));  // nop INSIDE blob
    return r;
}
#endif

// ---------------------------------------------------------------------------
// proj_kernel (R12 structure + float4 W staging): one of {k,q,v} = x @ W,
// all-fp16 inputs. Wk pre-scaled by log2e so flash uses exp2 directly.
// grid (512, 3), block 256, ONE barrier phase.
// R14 LESSON: W-fragments straight from global regressed — keep LDS staging.
// R16 LESSON: wprep/WoT out regressed (extra launch + scattered loads);
// float4 W staging kept (fewer VMEM instructions, same bytes).
// ---------------------------------------------------------------------------
__global__ __launch_bounds__(256) void proj_kernel(
    const float* __restrict__ x,
    const float* __restrict__ Wk, const float* __restrict__ Wq,
    const float* __restrict__ Wv,
    _Float16* __restrict__ k_ws, _Float16* __restrict__ q_ws,
    __bf16* __restrict__ vT_ws)
{
    const int m = blockIdx.y;
    const int r0 = blockIdx.x * 64;
    const float* W = (m == 0) ? Wk : (m == 1) ? Wq : Wv;
    const float wscale = (m == 0) ? LOG2E : 1.0f;

    __shared__ _Float16 wt[64][266];   // W^T [col][k]

    for (int idx = threadIdx.x; idx < 64 * 64; idx += 256) {
        int c4 = (idx & 15) * 4, k = idx >> 4;
        float4 w4 = *(const float4*)&W[k * 64 + c4];
        wt[c4 + 0][k] = (_Float16)(w4.x * wscale);
        wt[c4 + 1][k] = (_Float16)(w4.y * wscale);
        wt[c4 + 2][k] = (_Float16)(w4.z * wscale);
        wt[c4 + 3][k] = (_Float16)(w4.w * wscale);
    }

    const int lane = threadIdx.x & 63;
    const int wv = threadIdx.x >> 6;
    const int kbase = ((lane >> 4) & 3) * 8;
    const int arow = r0 + wv * 16 + (lane & 15);
    const float* xrow = x + (size_t)arow * CIN;

    f16x8 a[8];
    #pragma unroll
    for (int kk = 0; kk < 8; ++kk) {
        const float4* xp = (const float4*)(xrow + kk * 32 + kbase);
        float4 x0 = xp[0], x1 = xp[1];
        float xs[8] = {x0.x, x0.y, x0.z, x0.w, x1.x, x1.y, x1.z, x1.w};
        #pragma unroll
        for (int e = 0; e < 8; ++e) a[kk][e] = (_Float16)xs[e];
    }
    __syncthreads();

    f32x4 acc[4] = {f32x4{0,0,0,0}, f32x4{0,0,0,0}, f32x4{0,0,0,0}, f32x4{0,0,0,0}};
    #pragma unroll
    for (int kk = 0; kk < 8; ++kk) {
        #pragma unroll
        for (int nt = 0; nt < 4; ++nt) {
            f16x8 b = *(const f16x8*)&wt[(lane & 15) + 16 * nt][kk * 32 + kbase];
            acc[nt] = MFMA_F16(a[kk], b, acc[nt]);
        }
    }

    const int rloc = wv * 16 + ((lane >> 4) & 3) * 4;
    if (m < 2) {
        __syncthreads();
        _Float16* rp = &wt[0][0];          // viewed as [64][72]
        #pragma unroll
        for (int nt = 0; nt < 4; ++nt)
            #pragma unroll
            for (int r = 0; r < 4; ++r)
                rp[(rloc + r) * 72 + (lane & 15) + 16 * nt] = (_Float16)acc[nt][r];
        __syncthreads();
        _Float16* dst = (m == 0) ? k_ws : q_ws;
        const int row = threadIdx.x >> 3, c0 = (threadIdx.x & 7) * 8;
        #pragma unroll
        for (int h = 0; h < 2; ++h) {
            uint4 v = *(const uint4*)&rp[(row + 32 * h) * 72 + c0];
            *(uint4*)(dst + (size_t)(r0 + row + 32 * h) * CMID + c0) = v;
        }
    } else {
        const int rrow = r0 + rloc;
        const int b = rrow >> 12;
        const int n = rrow & (NPOS - 1);
        #pragma unroll
        for (int nt = 0; nt < 4; ++nt) {
            int cv = (lane & 15) + 16 * nt;
            union { __bf16 h[4]; uint2 u; } pk;
            #pragma unroll
            for (int r = 0; r < 4; ++r) pk.h[r] = (__bf16)acc[nt][r];
            *(uint2*)(vT_ws + ((size_t)b * CMID + cv) * NPOS + n) = pk.u;
        }
    }
}

// ---------------------------------------------------------------------------
// flash_kernel: EXACT R12 structure (proven 45.9 us). Streaming attention,
// 32x32 swapped-QK^T, in-register P, 8 waves x 32 i-rows (block=512),
// double-buffered tiles, issue-early/write-late staging, VALU den.
// (den-MFMA, setprio, nsplit=8, i=64/wave all regressed — R7/R10/R13.)
// grid (16, 8, NSPLIT).
// ---------------------------------------------------------------------------
__global__ __launch_bounds__(512, 4) void flash_kernel(
    const _Float16* __restrict__ k_ws,  // [32768][64]
    const _Float16* __restrict__ q_ws,  // [32768][64]
    const __bf16* __restrict__ vT_ws,   // [8][64][4096]
    __bf16* __restrict__ po,            // [NSPLIT][32768][64]
    float* __restrict__ pden)           // [NSPLIT][32768]
{
    const int b = blockIdx.y;
    const int i0 = blockIdx.x * 256;
    const int sblk = blockIdx.z;
    const int jbase = sblk * (NPOS / NSPLIT);
    const int lane = threadIdx.x & 63;
    const int wv = threadIdx.x >> 6;    // 0..7
    const int l31 = lane & 31;
    const int g = lane >> 5;

    __shared__ _Float16 qt[2][64][72];
    __shared__ __bf16 vt[2][64][72];

    // wave's 32 k-rows as B-fragments
    f16x8 kf[4];
    {
        const _Float16* kp =
            k_ws + ((size_t)(b * NPOS + i0 + wv * 32 + l31)) * CMID + g * 8;
        #pragma unroll
        for (int c = 0; c < 4; ++c) kf[c] = *(const f16x8*)(kp + c * 16);
    }

    f32x16 o0 = {0,0,0,0,0,0,0,0,0,0,0,0,0,0,0,0};
    f32x16 o1 = {0,0,0,0,0,0,0,0,0,0,0,0,0,0,0,0};
    float den = 0.f;

    // staging map: 512 threads x 16B = one 64x64 fp16/bf16 tile
    const int r = threadIdx.x >> 3, c0 = (threadIdx.x & 7) * 8;
    uint4 nq, nv;

    // prologue: tile 0
    {
        nq = *(const uint4*)(q_ws + ((size_t)(b * NPOS + jbase + r)) * CMID + c0);
        nv = *(const uint4*)(vT_ws + ((size_t)b * CMID + r) * NPOS + jbase + c0);
        *(uint4*)&qt[0][r][c0] = nq;
        *(uint4*)&vt[0][r][c0] = nv;
    }
    __syncthreads();

    const int NT = (NPOS / NSPLIT) / 64;  // 16
    for (int t = 0; t < NT; ++t) {
        const int cur = t & 1;
        if (t + 1 < NT) {   // issue next-tile loads early
            int j1 = jbase + (t + 1) * 64;
            nq = *(const uint4*)(q_ws + ((size_t)(b * NPOS + j1 + r)) * CMID + c0);
            nv = *(const uint4*)(vT_ws + ((size_t)b * CMID + r) * NPOS + j1 + c0);
        }

        #pragma unroll
        for (int jj = 0; jj < 2; ++jj) {
            f16x8 aq[4];
            #pragma unroll
            for (int c = 0; c < 4; ++c)
                aq[c] = *(const f16x8*)&qt[cur][jj * 32 + l31][c * 16 + g * 8];
            bf16_8 bv00 = *(const bf16_8*)&vt[cur][l31][jj * 32 + g * 8];
            bf16_8 bv01 = *(const bf16_8*)&vt[cur][l31][jj * 32 + 16 + g * 8];
            bf16_8 bv10 = *(const bf16_8*)&vt[cur][32 + l31][jj * 32 + g * 8];
            bf16_8 bv11 = *(const bf16_8*)&vt[cur][32 + l31][jj * 32 + 16 + g * 8];

            f32x16 s = {0,0,0,0,0,0,0,0,0,0,0,0,0,0,0,0};
            s = MFMA32_F16(aq[0], kf[0], s);
            s = MFMA32_F16(aq[1], kf[1], s);
            s = MFMA32_F16(aq[2], kf[2], s);
            s = MFMA32_F16(aq[3], kf[3], s);

            unsigned pk[8];
            #pragma unroll
            for (int m = 0; m < 8; ++m) {
                float p0 = fexp2(s[2 * m]);
                float p1 = fexp2(s[2 * m + 1]);
                den += p0 + p1;
                union { __bf16 h[2]; unsigned u; } w;
                w.h[0] = (__bf16)p0; w.h[1] = (__bf16)p1;
                pk[m] = w.u;
            }
            swaplane32(pk[0], pk[2]); swaplane32(pk[1], pk[3]);
            swaplane32(pk[4], pk[6]); swaplane32(pk[5], pk[7]);
            union { unsigned u[4]; bf16_8 v; } pa0, pa1;
            pa0.u[0] = pk[0]; pa0.u[1] = pk[1]; pa0.u[2] = pk[2]; pa0.u[3] = pk[3];
            pa1.u[0] = pk[4]; pa1.u[1] = pk[5]; pa1.u[2] = pk[6]; pa1.u[3] = pk[7];

            o0 = MFMA32_BF(pa0.v, bv00, o0);
            o0 = MFMA32_BF(pa1.v, bv01, o0);
            o1 = MFMA32_BF(pa0.v, bv10, o1);
            o1 = MFMA32_BF(pa1.v, bv11, o1);
        }

        if (t + 1 < NT) {   // write-late into the other buffer
            const int nb = cur ^ 1;
            *(uint4*)&qt[nb][r][c0] = nq;
            *(uint4*)&vt[nb][r][c0] = nv;
        }
        __syncthreads();
    }

    den += __shfl_xor(den, 32);

    const size_t rowb = (size_t)b * NPOS + i0 + wv * 32;
    if (lane < 32)
        pden[(size_t)sblk * NROWS + rowb + lane] = den;

    #pragma unroll
    for (int reg = 0; reg < 16; ++reg) {
        int il = (reg & 3) + 8 * (reg >> 2) + 4 * g;
        size_t base = ((size_t)sblk * NROWS + rowb + il) * CMID + l31;
        po[base]      = (__bf16)o0[reg];
        po[base + 32] = (__bf16)o1[reg];
    }
}

// ---------------------------------------------------------------------------
// out_kernel (R15-proven v2): 64 rows per block (grid 512) — Wo
// register-preload amortized 4x. Scalar Wo loads are broadcast-friendly
// (16 lanes share each dword -> 1 L2 transaction); R16's WoT 16B-stride
// loads regressed. Combine j-split partials (uint2-vectorized) -> at bf16
// -> rowgroup-looped MFMA attn @ Wo -> fused BatchNorm -> direct stores.
// block 256 (4 waves, wave wv owns cols wv*64..+63).
// ---------------------------------------------------------------------------
__global__ __launch_bounds__(256) void out_kernel(
    const __bf16* __restrict__ po,      // [NSPLIT][32768][64]
    const float* __restrict__ pden,     // [NSPLIT][32768]
    const float* __restrict__ Wo,       // [64][256]
    const float* __restrict__ gamma, const float* __restrict__ beta,
    const float* __restrict__ mmean, const float* __restrict__ mvar,
    float* __restrict__ out)            // [32768][256]
{
    const int r0 = blockIdx.x * 64;
    const int t = threadIdx.x;
    const int lane = t & 63;
    const int wv = t >> 6;
    const int n0 = wv * 64;

    __shared__ __bf16 at[64][72];
    __shared__ float dinv[64];

    // Wo B-fragments from global (L2-hot), bf16 cast — issued early
    bf16_8 wb[4][2];
    #pragma unroll
    for (int nt = 0; nt < 4; ++nt) {
        int col = n0 + nt * 16 + (lane & 15);
        #pragma unroll
        for (int ch = 0; ch < 2; ++ch)
            #pragma unroll
            for (int e = 0; e < 8; ++e)
                wb[nt][ch][e] = (__bf16)Wo[(ch * 32 + (lane >> 4) * 8 + e) * OC + col];
    }

    // BN constants per owned column (4 cols/thread)
    float scs[4], shs[4];
    #pragma unroll
    for (int nt = 0; nt < 4; ++nt) {
        int col = n0 + nt * 16 + (lane & 15);
        scs[nt] = gamma[col] * rsqrtf(mvar[col] + 1e-3f);
        shs[nt] = beta[col] - mmean[col] * scs[nt];
    }

    if (t < 64) {
        float d = 0.f;
        #pragma unroll
        for (int s = 0; s < NSPLIT; ++s) d += pden[(size_t)s * NROWS + r0 + t];
        dinv[t] = 1.0f / d;
    }
    __syncthreads();

    // vectorized combine: 64x64 = 1024 quads, 4 per thread
    #pragma unroll
    for (int q = 0; q < 4; ++q) {
        int quad = t + q * 256;
        int rr = quad >> 4, c4 = (quad & 15) * 4;
        float s0 = 0.f, s1 = 0.f, s2 = 0.f, s3 = 0.f;
        #pragma unroll
        for (int s = 0; s < NSPLIT; ++s) {
            union { uint2 u; __bf16 h[4]; } qq;
            qq.u = *(const uint2*)&po[((size_t)s * NROWS + r0 + rr) * CMID + c4];
            s0 += (float)qq.h[0]; s1 += (float)qq.h[1];
            s2 += (float)qq.h[2]; s3 += (float)qq.h[3];
        }
        float di = dinv[rr];
        union { __bf16 h[4]; uint2 u; } o;
        o.h[0] = (__bf16)(s0 * di); o.h[1] = (__bf16)(s1 * di);
        o.h[2] = (__bf16)(s2 * di); o.h[3] = (__bf16)(s3 * di);
        *(uint2*)&at[rr][c4] = o.u;
    }
    __syncthreads();

    // rowgroup-looped MFMA: 4 groups of 16 rows; acc live range = 16 f32
    #pragma unroll
    for (int rg = 0; rg < 4; ++rg) {
        bf16_8 a0 = *(const bf16_8*)&at[rg * 16 + (lane & 15)][(lane >> 4) * 8];
        bf16_8 a1 = *(const bf16_8*)&at[rg * 16 + (lane & 15)][32 + (lane >> 4) * 8];
        #pragma unroll
        for (int nt = 0; nt < 4; ++nt) {
            int col = n0 + nt * 16 + (lane & 15);
            f32x4 acc = {0.f, 0.f, 0.f, 0.f};
            acc = MFMA_BF(a0, wb[nt][0], acc);
            acc = MFMA_BF(a1, wb[nt][1], acc);
            int rl = rg * 16 + (lane >> 4) * 4;
            #pragma unroll
            for (int rr = 0; rr < 4; ++rr)
                out[(size_t)(r0 + rl + rr) * OC + col] = acc[rr] * scs[nt] + shs[nt];
        }
    }
}

// ---------------------------------------------------------------------------
extern "C" void kernel_launch(void* const* d_in, const int* in_sizes, int n_in,
                              void* d_out, int out_size, void* d_ws, size_t ws_size,
                              hipStream_t stream) {
    const float* x     = (const float*)d_in[0];
    const float* Wk    = (const float*)d_in[1];
    const float* Wq    = (const float*)d_in[2];
    const float* Wv    = (const float*)d_in[3];
    const float* Wo    = (const float*)d_in[4];
    const float* gamma = (const float*)d_in[5];
    const float* beta  = (const float*)d_in[6];
    const float* mmean = (const float*)d_in[7];
    const float* mvar  = (const float*)d_in[8];
    float* out = (float*)d_out;

    // k/q/vT live in d_out (32 MiB): dead before out_kernel writes out.
    char* ob = (char*)d_out;
    const size_t MB4 = (size_t)NROWS * CMID * 2;   // 4 MiB
    _Float16* k_ws = (_Float16*)ob;                // 4 MiB
    _Float16* q_ws = (_Float16*)(ob + MB4);        // 4 MiB
    __bf16*   vT   = (__bf16*)(ob + 2 * MB4);      // 4 MiB

    __bf16* po   = (__bf16*)d_ws;                                 // 16 MiB
    float*  pden = (float*)((char*)d_ws + (size_t)NSPLIT * MB4);  // 512 KiB

    proj_kernel<<<dim3(512, 3), 256, 0, stream>>>(x, Wk, Wq, Wv, k_ws, q_ws, vT);
    flash_kernel<<<dim3(16, 8, NSPLIT), 512, 0, stream>>>(k_ws, q_ws, vT, po, pden);
    out_kernel<<<512, 256, 0, stream>>>(po, pden, Wo, gamma, beta, mmean, mvar, out);
}

// Round 18
// 82.534 us; speedup vs baseline: 1.0784x; 1.0229x over previous
//
#include <hip/hip_runtime.h>
#include <hip/hip_bf16.h>

typedef __bf16 bf16_8 __attribute__((ext_vector_type(8)));
typedef _Float16 f16x8 __attribute__((ext_vector_type(8)));
typedef float f32x4 __attribute__((ext_vector_type(4)));
typedef float f32x16 __attribute__((ext_vector_type(16)));

#define MFMA_BF(A, B, C)    __builtin_amdgcn_mfma_f32_16x16x32_bf16(A, B, C, 0, 0, 0)
#define MFMA_F16(A, B, C)   __builtin_amdgcn_mfma_f32_16x16x32_f16(A, B, C, 0, 0, 0)
#define MFMA32_F16(A, B, C) __builtin_amdgcn_mfma_f32_32x32x16_f16(A, B, C, 0, 0, 0)
#define MFMA32_BF(A, B, C)  __builtin_amdgcn_mfma_f32_32x32x16_bf16(A, B, C, 0, 0, 0)

#define BATCH 8
#define NPOS 4096            // 64*64 spatial
#define CIN 256
#define CMID 64
#define OC 256
#define NROWS (BATCH * NPOS) // 32768
#define NSPLIT 4             // j-split (nsplit=8 regressed: reg cap is 16 waves/CU)
#define LOG2E 1.44269504088896f

// lane i <-> lane i+32 register swap (hi half of a <-> lo half of b)
__device__ inline void swaplane32(unsigned& a, unsigned& b) {
    asm volatile("v_permlane32_swap_b32 %0, %1" : "+v"(a), "+v"(b));
}

// single-instruction 2^x. R11 LESSON: bare inline-asm v_exp_f32 is WRONG —
// trans-op forwarding hazard invisible to the compiler. Builtin is safe.
#if __has_builtin(__builtin_amdgcn_exp2f)
__device__ inline float fexp2(float x) { return __builtin_amdgcn_exp2f(x); }
#else
__device__ inline float fexp2(float x) {
    float r;
    asm("v_exp_f32 %0, %1\n\ts_nop 1" : "=v"(r) : "v"(x));  // nop INSIDE blob
    return r;
}
#endif

// ---------------------------------------------------------------------------
// proj_kernel (fused-m, R18): k,q,v = x @ {Wk,Wq,Wv} with x read ONCE
// (grid 512 not (512,3): cuts x traffic 100 -> 33.5 MB). One 34 KB fp16
// W buffer (4 blocks/CU), float4 conflict-free staging, 1x MFMA per m.
// k,q accumulators held in VGPRs across the m-loop; both repacked into
// disjoint halves of the reused wt buffer (2 extra barriers total).
// R6 LESSON (fused-m failure) causes fixed: was 68KB LDS + 3x MFMA + scalar
// staging. R14 LESSON: W-fragments straight from global regressed.
// Wk pre-scaled by log2e so flash uses exp2 directly.
// ---------------------------------------------------------------------------
__global__ __launch_bounds__(256) void proj_kernel(
    const float* __restrict__ x,
    const float* __restrict__ Wk, const float* __restrict__ Wq,
    const float* __restrict__ Wv,
    _Float16* __restrict__ k_ws, _Float16* __restrict__ q_ws,
    __bf16* __restrict__ vT_ws)
{
    const int r0 = blockIdx.x * 64;

    __shared__ _Float16 wt[64][266];   // W^T [col][k]; later reused as repack

    const int lane = threadIdx.x & 63;
    const int wv = threadIdx.x >> 6;
    const int kbase = ((lane >> 4) & 3) * 8;
    const int arow = r0 + wv * 16 + (lane & 15);
    const float* xrow = x + (size_t)arow * CIN;

    // x tile -> fp16 registers, ONCE
    f16x8 a[8];
    #pragma unroll
    for (int kk = 0; kk < 8; ++kk) {
        const float4* xp = (const float4*)(xrow + kk * 32 + kbase);
        float4 x0 = xp[0], x1 = xp[1];
        float xs[8] = {x0.x, x0.y, x0.z, x0.w, x1.x, x1.y, x1.z, x1.w};
        #pragma unroll
        for (int e = 0; e < 8; ++e) a[kk][e] = (_Float16)xs[e];
    }

    const float* Ws[3] = {Wk, Wq, Wv};
    f32x4 acck[4], accq[4];
    const int rloc = wv * 16 + ((lane >> 4) & 3) * 4;

    #pragma unroll
    for (int m = 0; m < 3; ++m) {
        if (m) __syncthreads();            // previous phase's wt reads done
        const float wscale = (m == 0) ? LOG2E : 1.0f;
        for (int idx = threadIdx.x; idx < 64 * 64; idx += 256) {
            int c4 = (idx & 15) * 4, k = idx >> 4;
            float4 w4 = *(const float4*)&Ws[m][k * 64 + c4];
            wt[c4 + 0][k] = (_Float16)(w4.x * wscale);
            wt[c4 + 1][k] = (_Float16)(w4.y * wscale);
            wt[c4 + 2][k] = (_Float16)(w4.z * wscale);
            wt[c4 + 3][k] = (_Float16)(w4.w * wscale);
        }
        __syncthreads();

        f32x4 acc[4] = {f32x4{0,0,0,0}, f32x4{0,0,0,0}, f32x4{0,0,0,0}, f32x4{0,0,0,0}};
        #pragma unroll
        for (int kk = 0; kk < 8; ++kk) {
            #pragma unroll
            for (int nt = 0; nt < 4; ++nt) {
                f16x8 b = *(const f16x8*)&wt[(lane & 15) + 16 * nt][kk * 32 + kbase];
                acc[nt] = MFMA_F16(a[kk], b, acc[nt]);
            }
        }

        if (m == 0) {
            #pragma unroll
            for (int nt = 0; nt < 4; ++nt) acck[nt] = acc[nt];
        } else if (m == 1) {
            #pragma unroll
            for (int nt = 0; nt < 4; ++nt) accq[nt] = acc[nt];
        } else {
            const int rrow = r0 + rloc;
            const int b = rrow >> 12;
            const int n = rrow & (NPOS - 1);
            #pragma unroll
            for (int nt = 0; nt < 4; ++nt) {
                int cv = (lane & 15) + 16 * nt;
                union { __bf16 h[4]; uint2 u; } pk;
                #pragma unroll
                for (int r = 0; r < 4; ++r) pk.h[r] = (__bf16)acc[nt][r];
                *(uint2*)(vT_ws + ((size_t)b * CMID + cv) * NPOS + n) = pk.u;
            }
        }
    }

    // repack k,q into disjoint halves of wt (viewed flat as 2x [64][72])
    __syncthreads();                       // all m=2 wt reads done
    _Float16* rpk = &wt[0][0];
    _Float16* rpq = rpk + 64 * 72;
    #pragma unroll
    for (int nt = 0; nt < 4; ++nt)
        #pragma unroll
        for (int r = 0; r < 4; ++r) {
            int off = (rloc + r) * 72 + (lane & 15) + 16 * nt;
            rpk[off] = (_Float16)acck[nt][r];
            rpq[off] = (_Float16)accq[nt][r];
        }
    __syncthreads();
    const int row = threadIdx.x >> 3, c0 = (threadIdx.x & 7) * 8;
    #pragma unroll
    for (int h = 0; h < 2; ++h) {
        uint4 vk = *(const uint4*)&rpk[(row + 32 * h) * 72 + c0];
        *(uint4*)(k_ws + (size_t)(r0 + row + 32 * h) * CMID + c0) = vk;
        uint4 vq = *(const uint4*)&rpq[(row + 32 * h) * 72 + c0];
        *(uint4*)(q_ws + (size_t)(r0 + row + 32 * h) * CMID + c0) = vq;
    }
}

// ---------------------------------------------------------------------------
// flash_kernel: EXACT R12 structure (proven 45.9 us). Streaming attention,
// 32x32 swapped-QK^T, in-register P, 8 waves x 32 i-rows (block=512),
// double-buffered tiles, issue-early/write-late staging, VALU den.
// (den-MFMA, setprio, nsplit=8, i=64/wave all regressed — R7/R10/R13.)
// grid (16, 8, NSPLIT).
// ---------------------------------------------------------------------------
__global__ __launch_bounds__(512, 4) void flash_kernel(
    const _Float16* __restrict__ k_ws,  // [32768][64]
    const _Float16* __restrict__ q_ws,  // [32768][64]
    const __bf16* __restrict__ vT_ws,   // [8][64][4096]
    __bf16* __restrict__ po,            // [NSPLIT][32768][64]
    float* __restrict__ pden)           // [NSPLIT][32768]
{
    const int b = blockIdx.y;
    const int i0 = blockIdx.x * 256;
    const int sblk = blockIdx.z;
    const int jbase = sblk * (NPOS / NSPLIT);
    const int lane = threadIdx.x & 63;
    const int wv = threadIdx.x >> 6;    // 0..7
    const int l31 = lane & 31;
    const int g = lane >> 5;

    __shared__ _Float16 qt[2][64][72];
    __shared__ __bf16 vt[2][64][72];

    // wave's 32 k-rows as B-fragments
    f16x8 kf[4];
    {
        const _Float16* kp =
            k_ws + ((size_t)(b * NPOS + i0 + wv * 32 + l31)) * CMID + g * 8;
        #pragma unroll
        for (int c = 0; c < 4; ++c) kf[c] = *(const f16x8*)(kp + c * 16);
    }

    f32x16 o0 = {0,0,0,0,0,0,0,0,0,0,0,0,0,0,0,0};
    f32x16 o1 = {0,0,0,0,0,0,0,0,0,0,0,0,0,0,0,0};
    float den = 0.f;

    // staging map: 512 threads x 16B = one 64x64 fp16/bf16 tile
    const int r = threadIdx.x >> 3, c0 = (threadIdx.x & 7) * 8;
    uint4 nq, nv;

    // prologue: tile 0
    {
        nq = *(const uint4*)(q_ws + ((size_t)(b * NPOS + jbase + r)) * CMID + c0);
        nv = *(const uint4*)(vT_ws + ((size_t)b * CMID + r) * NPOS + jbase + c0);
        *(uint4*)&qt[0][r][c0] = nq;
        *(uint4*)&vt[0][r][c0] = nv;
    }
    __syncthreads();

    const int NT = (NPOS / NSPLIT) / 64;  // 16
    for (int t = 0; t < NT; ++t) {
        const int cur = t & 1;
        if (t + 1 < NT) {   // issue next-tile loads early
            int j1 = jbase + (t + 1) * 64;
            nq = *(const uint4*)(q_ws + ((size_t)(b * NPOS + j1 + r)) * CMID + c0);
            nv = *(const uint4*)(vT_ws + ((size_t)b * CMID + r) * NPOS + j1 + c0);
        }

        #pragma unroll
        for (int jj = 0; jj < 2; ++jj) {
            f16x8 aq[4];
            #pragma unroll
            for (int c = 0; c < 4; ++c)
                aq[c] = *(const f16x8*)&qt[cur][jj * 32 + l31][c * 16 + g * 8];
            bf16_8 bv00 = *(const bf16_8*)&vt[cur][l31][jj * 32 + g * 8];
            bf16_8 bv01 = *(const bf16_8*)&vt[cur][l31][jj * 32 + 16 + g * 8];
            bf16_8 bv10 = *(const bf16_8*)&vt[cur][32 + l31][jj * 32 + g * 8];
            bf16_8 bv11 = *(const bf16_8*)&vt[cur][32 + l31][jj * 32 + 16 + g * 8];

            f32x16 s = {0,0,0,0,0,0,0,0,0,0,0,0,0,0,0,0};
            s = MFMA32_F16(aq[0], kf[0], s);
            s = MFMA32_F16(aq[1], kf[1], s);
            s = MFMA32_F16(aq[2], kf[2], s);
            s = MFMA32_F16(aq[3], kf[3], s);

            unsigned pk[8];
            #pragma unroll
            for (int m = 0; m < 8; ++m) {
                float p0 = fexp2(s[2 * m]);
                float p1 = fexp2(s[2 * m + 1]);
                den += p0 + p1;
                union { __bf16 h[2]; unsigned u; } w;
                w.h[0] = (__bf16)p0; w.h[1] = (__bf16)p1;
                pk[m] = w.u;
            }
            swaplane32(pk[0], pk[2]); swaplane32(pk[1], pk[3]);
            swaplane32(pk[4], pk[6]); swaplane32(pk[5], pk[7]);
            union { unsigned u[4]; bf16_8 v; } pa0, pa1;
            pa0.u[0] = pk[0]; pa0.u[1] = pk[1]; pa0.u[2] = pk[2]; pa0.u[3] = pk[3];
            pa1.u[0] = pk[4]; pa1.u[1] = pk[5]; pa1.u[2] = pk[6]; pa1.u[3] = pk[7];

            o0 = MFMA32_BF(pa0.v, bv00, o0);
            o0 = MFMA32_BF(pa1.v, bv01, o0);
            o1 = MFMA32_BF(pa0.v, bv10, o1);
            o1 = MFMA32_BF(pa1.v, bv11, o1);
        }

        if (t + 1 < NT) {   // write-late into the other buffer
            const int nb = cur ^ 1;
            *(uint4*)&qt[nb][r][c0] = nq;
            *(uint4*)&vt[nb][r][c0] = nv;
        }
        __syncthreads();
    }

    den += __shfl_xor(den, 32);

    const size_t rowb = (size_t)b * NPOS + i0 + wv * 32;
    if (lane < 32)
        pden[(size_t)sblk * NROWS + rowb + lane] = den;

    #pragma unroll
    for (int reg = 0; reg < 16; ++reg) {
        int il = (reg & 3) + 8 * (reg >> 2) + 4 * g;
        size_t base = ((size_t)sblk * NROWS + rowb + il) * CMID + l31;
        po[base]      = (__bf16)o0[reg];
        po[base + 32] = (__bf16)o1[reg];
    }
}

// ---------------------------------------------------------------------------
// out_kernel (R15-proven v2): 64 rows per block (grid 512) — Wo
// register-preload amortized 4x. Scalar Wo loads are broadcast-friendly
// (16 lanes share each dword -> 1 L2 transaction); R16's WoT 16B-stride
// loads regressed. Combine j-split partials (uint2-vectorized) -> at bf16
// -> rowgroup-looped MFMA attn @ Wo -> fused BatchNorm -> direct stores.
// block 256 (4 waves, wave wv owns cols wv*64..+63).
// ---------------------------------------------------------------------------
__global__ __launch_bounds__(256) void out_kernel(
    const __bf16* __restrict__ po,      // [NSPLIT][32768][64]
    const float* __restrict__ pden,     // [NSPLIT][32768]
    const float* __restrict__ Wo,       // [64][256]
    const float* __restrict__ gamma, const float* __restrict__ beta,
    const float* __restrict__ mmean, const float* __restrict__ mvar,
    float* __restrict__ out)            // [32768][256]
{
    const int r0 = blockIdx.x * 64;
    const int t = threadIdx.x;
    const int lane = t & 63;
    const int wv = t >> 6;
    const int n0 = wv * 64;

    __shared__ __bf16 at[64][72];
    __shared__ float dinv[64];

    // Wo B-fragments from global (L2-hot), bf16 cast — issued early
    bf16_8 wb[4][2];
    #pragma unroll
    for (int nt = 0; nt < 4; ++nt) {
        int col = n0 + nt * 16 + (lane & 15);
        #pragma unroll
        for (int ch = 0; ch < 2; ++ch)
            #pragma unroll
            for (int e = 0; e < 8; ++e)
                wb[nt][ch][e] = (__bf16)Wo[(ch * 32 + (lane >> 4) * 8 + e) * OC + col];
    }

    // BN constants per owned column (4 cols/thread)
    float scs[4], shs[4];
    #pragma unroll
    for (int nt = 0; nt < 4; ++nt) {
        int col = n0 + nt * 16 + (lane & 15);
        scs[nt] = gamma[col] * rsqrtf(mvar[col] + 1e-3f);
        shs[nt] = beta[col] - mmean[col] * scs[nt];
    }

    if (t < 64) {
        float d = 0.f;
        #pragma unroll
        for (int s = 0; s < NSPLIT; ++s) d += pden[(size_t)s * NROWS + r0 + t];
        dinv[t] = 1.0f / d;
    }
    __syncthreads();

    // vectorized combine: 64x64 = 1024 quads, 4 per thread
    #pragma unroll
    for (int q = 0; q < 4; ++q) {
        int quad = t + q * 256;
        int rr = quad >> 4, c4 = (quad & 15) * 4;
        float s0 = 0.f, s1 = 0.f, s2 = 0.f, s3 = 0.f;
        #pragma unroll
        for (int s = 0; s < NSPLIT; ++s) {
            union { uint2 u; __bf16 h[4]; } qq;
            qq.u = *(const uint2*)&po[((size_t)s * NROWS + r0 + rr) * CMID + c4];
            s0 += (float)qq.h[0]; s1 += (float)qq.h[1];
            s2 += (float)qq.h[2]; s3 += (float)qq.h[3];
        }
        float di = dinv[rr];
        union { __bf16 h[4]; uint2 u; } o;
        o.h[0] = (__bf16)(s0 * di); o.h[1] = (__bf16)(s1 * di);
        o.h[2] = (__bf16)(s2 * di); o.h[3] = (__bf16)(s3 * di);
        *(uint2*)&at[rr][c4] = o.u;
    }
    __syncthreads();

    // rowgroup-looped MFMA: 4 groups of 16 rows; acc live range = 16 f32
    #pragma unroll
    for (int rg = 0; rg < 4; ++rg) {
        bf16_8 a0 = *(const bf16_8*)&at[rg * 16 + (lane & 15)][(lane >> 4) * 8];
        bf16_8 a1 = *(const bf16_8*)&at[rg * 16 + (lane & 15)][32 + (lane >> 4) * 8];
        #pragma unroll
        for (int nt = 0; nt < 4; ++nt) {
            int col = n0 + nt * 16 + (lane & 15);
            f32x4 acc = {0.f, 0.f, 0.f, 0.f};
            acc = MFMA_BF(a0, wb[nt][0], acc);
            acc = MFMA_BF(a1, wb[nt][1], acc);
            int rl = rg * 16 + (lane >> 4) * 4;
            #pragma unroll
            for (int rr = 0; rr < 4; ++rr)
                out[(size_t)(r0 + rl + rr) * OC + col] = acc[rr] * scs[nt] + shs[nt];
        }
    }
}

// ---------------------------------------------------------------------------
extern "C" void kernel_launch(void* const* d_in, const int* in_sizes, int n_in,
                              void* d_out, int out_size, void* d_ws, size_t ws_size,
                              hipStream_t stream) {
    const float* x     = (const float*)d_in[0];
    const float* Wk    = (const float*)d_in[1];
    const float* Wq    = (const float*)d_in[2];
    const float* Wv    = (const float*)d_in[3];
    const float* Wo    = (const float*)d_in[4];
    const float* gamma = (const float*)d_in[5];
    const float* beta  = (const float*)d_in[6];
    const float* mmean = (const float*)d_in[7];
    const float* mvar  = (const float*)d_in[8];
    float* out = (float*)d_out;

    // k/q/vT live in d_out (32 MiB): dead before out_kernel writes out.
    char* ob = (char*)d_out;
    const size_t MB4 = (size_t)NROWS * CMID * 2;   // 4 MiB
    _Float16* k_ws = (_Float16*)ob;                // 4 MiB
    _Float16* q_ws = (_Float16*)(ob + MB4);        // 4 MiB
    __bf16*   vT   = (__bf16*)(ob + 2 * MB4);      // 4 MiB

    __bf16* po   = (__bf16*)d_ws;                                 // 16 MiB
    float*  pden = (float*)((char*)d_ws + (size_t)NSPLIT * MB4);  // 512 KiB

    proj_kernel<<<512, 256, 0, stream>>>(x, Wk, Wq, Wv, k_ws, q_ws, vT);
    flash_kernel<<<dim3(16, 8, NSPLIT), 512, 0, stream>>>(k_ws, q_ws, vT, po, pden);
    out_kernel<<<512, 256, 0, stream>>>(po, pden, Wo, gamma, beta, mmean, mvar, out);
}

// Round 19
// 81.661 us; speedup vs baseline: 1.0900x; 1.0107x over previous
//
#include <hip/hip_runtime.h>
#include <hip/hip_bf16.h>

typedef __bf16 bf16_8 __attribute__((ext_vector_type(8)));
typedef _Float16 f16x8 __attribute__((ext_vector_type(8)));
typedef float f32x2 __attribute__((ext_vector_type(2)));
typedef float f32x4 __attribute__((ext_vector_type(4)));
typedef float f32x16 __attribute__((ext_vector_type(16)));

#define MFMA_BF(A, B, C)    __builtin_amdgcn_mfma_f32_16x16x32_bf16(A, B, C, 0, 0, 0)
#define MFMA_F16(A, B, C)   __builtin_amdgcn_mfma_f32_16x16x32_f16(A, B, C, 0, 0, 0)
#define MFMA32_F16(A, B, C) __builtin_amdgcn_mfma_f32_32x32x16_f16(A, B, C, 0, 0, 0)
#define MFMA32_BF(A, B, C)  __builtin_amdgcn_mfma_f32_32x32x16_bf16(A, B, C, 0, 0, 0)

#define BATCH 8
#define NPOS 4096            // 64*64 spatial
#define CIN 256
#define CMID 64
#define OC 256
#define NROWS (BATCH * NPOS) // 32768
#define NSPLIT 4             // j-split (nsplit=8 regressed: reg cap is 16 waves/CU)
#define LOG2E 1.44269504088896f

// lane i <-> lane i+32 register swap (hi half of a <-> lo half of b)
__device__ inline void swaplane32(unsigned& a, unsigned& b) {
    asm volatile("v_permlane32_swap_b32 %0, %1" : "+v"(a), "+v"(b));
}

// single-instruction 2^x. R11 LESSON: bare inline-asm v_exp_f32 is WRONG —
// trans-op forwarding hazard invisible to the compiler. Builtin is safe.
#if __has_builtin(__builtin_amdgcn_exp2f)
__device__ inline float fexp2(float x) { return __builtin_amdgcn_exp2f(x); }
#else
__device__ inline float fexp2(float x) {
    float r;
    asm("v_exp_f32 %0, %1\n\ts_nop 1" : "=v"(r) : "v"(x));  // nop INSIDE blob
    return r;
}
#endif

// ---------------------------------------------------------------------------
// proj_kernel (fused-m, R18-proven): k,q,v = x @ {Wk,Wq,Wv} with x read ONCE
// (grid 512). One 34 KB fp16 W buffer (4 blocks/CU), float4 conflict-free
// staging, 1x MFMA per m. k,q accumulators in VGPRs across the m-loop;
// repacked into disjoint halves of the reused wt buffer.
// Wk pre-scaled by log2e so flash uses exp2 directly.
// ---------------------------------------------------------------------------
__global__ __launch_bounds__(256) void proj_kernel(
    const float* __restrict__ x,
    const float* __restrict__ Wk, const float* __restrict__ Wq,
    const float* __restrict__ Wv,
    _Float16* __restrict__ k_ws, _Float16* __restrict__ q_ws,
    __bf16* __restrict__ vT_ws)
{
    const int r0 = blockIdx.x * 64;

    __shared__ _Float16 wt[64][266];   // W^T [col][k]; later reused as repack

    const int lane = threadIdx.x & 63;
    const int wv = threadIdx.x >> 6;
    const int kbase = ((lane >> 4) & 3) * 8;
    const int arow = r0 + wv * 16 + (lane & 15);
    const float* xrow = x + (size_t)arow * CIN;

    // x tile -> fp16 registers, ONCE
    f16x8 a[8];
    #pragma unroll
    for (int kk = 0; kk < 8; ++kk) {
        const float4* xp = (const float4*)(xrow + kk * 32 + kbase);
        float4 x0 = xp[0], x1 = xp[1];
        float xs[8] = {x0.x, x0.y, x0.z, x0.w, x1.x, x1.y, x1.z, x1.w};
        #pragma unroll
        for (int e = 0; e < 8; ++e) a[kk][e] = (_Float16)xs[e];
    }

    const float* Ws[3] = {Wk, Wq, Wv};
    f32x4 acck[4], accq[4];
    const int rloc = wv * 16 + ((lane >> 4) & 3) * 4;

    #pragma unroll
    for (int m = 0; m < 3; ++m) {
        if (m) __syncthreads();            // previous phase's wt reads done
        const float wscale = (m == 0) ? LOG2E : 1.0f;
        for (int idx = threadIdx.x; idx < 64 * 64; idx += 256) {
            int c4 = (idx & 15) * 4, k = idx >> 4;
            float4 w4 = *(const float4*)&Ws[m][k * 64 + c4];
            wt[c4 + 0][k] = (_Float16)(w4.x * wscale);
            wt[c4 + 1][k] = (_Float16)(w4.y * wscale);
            wt[c4 + 2][k] = (_Float16)(w4.z * wscale);
            wt[c4 + 3][k] = (_Float16)(w4.w * wscale);
        }
        __syncthreads();

        f32x4 acc[4] = {f32x4{0,0,0,0}, f32x4{0,0,0,0}, f32x4{0,0,0,0}, f32x4{0,0,0,0}};
        #pragma unroll
        for (int kk = 0; kk < 8; ++kk) {
            #pragma unroll
            for (int nt = 0; nt < 4; ++nt) {
                f16x8 b = *(const f16x8*)&wt[(lane & 15) + 16 * nt][kk * 32 + kbase];
                acc[nt] = MFMA_F16(a[kk], b, acc[nt]);
            }
        }

        if (m == 0) {
            #pragma unroll
            for (int nt = 0; nt < 4; ++nt) acck[nt] = acc[nt];
        } else if (m == 1) {
            #pragma unroll
            for (int nt = 0; nt < 4; ++nt) accq[nt] = acc[nt];
        } else {
            const int rrow = r0 + rloc;
            const int b = rrow >> 12;
            const int n = rrow & (NPOS - 1);
            #pragma unroll
            for (int nt = 0; nt < 4; ++nt) {
                int cv = (lane & 15) + 16 * nt;
                union { __bf16 h[4]; uint2 u; } pk;
                #pragma unroll
                for (int r = 0; r < 4; ++r) pk.h[r] = (__bf16)acc[nt][r];
                *(uint2*)(vT_ws + ((size_t)b * CMID + cv) * NPOS + n) = pk.u;
            }
        }
    }

    // repack k,q into disjoint halves of wt (viewed flat as 2x [64][72])
    __syncthreads();                       // all m=2 wt reads done
    _Float16* rpk = &wt[0][0];
    _Float16* rpq = rpk + 64 * 72;
    #pragma unroll
    for (int nt = 0; nt < 4; ++nt)
        #pragma unroll
        for (int r = 0; r < 4; ++r) {
            int off = (rloc + r) * 72 + (lane & 15) + 16 * nt;
            rpk[off] = (_Float16)acck[nt][r];
            rpq[off] = (_Float16)accq[nt][r];
        }
    __syncthreads();
    const int row = threadIdx.x >> 3, c0 = (threadIdx.x & 7) * 8;
    #pragma unroll
    for (int h = 0; h < 2; ++h) {
        uint4 vk = *(const uint4*)&rpk[(row + 32 * h) * 72 + c0];
        *(uint4*)(k_ws + (size_t)(r0 + row + 32 * h) * CMID + c0) = vk;
        uint4 vq = *(const uint4*)&rpq[(row + 32 * h) * 72 + c0];
        *(uint4*)(q_ws + (size_t)(r0 + row + 32 * h) * CMID + c0) = vq;
    }
}

// ---------------------------------------------------------------------------
// flash_kernel: R12 structure (proven 45.9 us) + den as f32x2 accumulator
// (v_pk_add_f32 path halves den-add issue; falls back to 2 scalar adds —
// no-worse). Streaming attention, 32x32 swapped-QK^T, in-register P,
// 8 waves x 32 i-rows (block=512), double-buffered tiles,
// issue-early/write-late staging. (den-MFMA, setprio, nsplit=8, i=64/wave
// all regressed — R7/R10/R13.) grid (16, 8, NSPLIT).
// ---------------------------------------------------------------------------
__global__ __launch_bounds__(512, 4) void flash_kernel(
    const _Float16* __restrict__ k_ws,  // [32768][64]
    const _Float16* __restrict__ q_ws,  // [32768][64]
    const __bf16* __restrict__ vT_ws,   // [8][64][4096]
    __bf16* __restrict__ po,            // [NSPLIT][32768][64]
    float* __restrict__ pden)           // [NSPLIT][32768]
{
    const int b = blockIdx.y;
    const int i0 = blockIdx.x * 256;
    const int sblk = blockIdx.z;
    const int jbase = sblk * (NPOS / NSPLIT);
    const int lane = threadIdx.x & 63;
    const int wv = threadIdx.x >> 6;    // 0..7
    const int l31 = lane & 31;
    const int g = lane >> 5;

    __shared__ _Float16 qt[2][64][72];
    __shared__ __bf16 vt[2][64][72];

    // wave's 32 k-rows as B-fragments
    f16x8 kf[4];
    {
        const _Float16* kp =
            k_ws + ((size_t)(b * NPOS + i0 + wv * 32 + l31)) * CMID + g * 8;
        #pragma unroll
        for (int c = 0; c < 4; ++c) kf[c] = *(const f16x8*)(kp + c * 16);
    }

    f32x16 o0 = {0,0,0,0,0,0,0,0,0,0,0,0,0,0,0,0};
    f32x16 o1 = {0,0,0,0,0,0,0,0,0,0,0,0,0,0,0,0};
    f32x2 den2 = {0.f, 0.f};

    // staging map: 512 threads x 16B = one 64x64 fp16/bf16 tile
    const int r = threadIdx.x >> 3, c0 = (threadIdx.x & 7) * 8;
    uint4 nq, nv;

    // prologue: tile 0
    {
        nq = *(const uint4*)(q_ws + ((size_t)(b * NPOS + jbase + r)) * CMID + c0);
        nv = *(const uint4*)(vT_ws + ((size_t)b * CMID + r) * NPOS + jbase + c0);
        *(uint4*)&qt[0][r][c0] = nq;
        *(uint4*)&vt[0][r][c0] = nv;
    }
    __syncthreads();

    const int NT = (NPOS / NSPLIT) / 64;  // 16
    for (int t = 0; t < NT; ++t) {
        const int cur = t & 1;
        if (t + 1 < NT) {   // issue next-tile loads early
            int j1 = jbase + (t + 1) * 64;
            nq = *(const uint4*)(q_ws + ((size_t)(b * NPOS + j1 + r)) * CMID + c0);
            nv = *(const uint4*)(vT_ws + ((size_t)b * CMID + r) * NPOS + j1 + c0);
        }

        #pragma unroll
        for (int jj = 0; jj < 2; ++jj) {
            f16x8 aq[4];
            #pragma unroll
            for (int c = 0; c < 4; ++c)
                aq[c] = *(const f16x8*)&qt[cur][jj * 32 + l31][c * 16 + g * 8];
            bf16_8 bv00 = *(const bf16_8*)&vt[cur][l31][jj * 32 + g * 8];
            bf16_8 bv01 = *(const bf16_8*)&vt[cur][l31][jj * 32 + 16 + g * 8];
            bf16_8 bv10 = *(const bf16_8*)&vt[cur][32 + l31][jj * 32 + g * 8];
            bf16_8 bv11 = *(const bf16_8*)&vt[cur][32 + l31][jj * 32 + 16 + g * 8];

            f32x16 s = {0,0,0,0,0,0,0,0,0,0,0,0,0,0,0,0};
            s = MFMA32_F16(aq[0], kf[0], s);
            s = MFMA32_F16(aq[1], kf[1], s);
            s = MFMA32_F16(aq[2], kf[2], s);
            s = MFMA32_F16(aq[3], kf[3], s);

            unsigned pk[8];
            #pragma unroll
            for (int m = 0; m < 8; ++m) {
                float p0 = fexp2(s[2 * m]);
                float p1 = fexp2(s[2 * m + 1]);
                den2 += (f32x2){p0, p1};
                union { __bf16 h[2]; unsigned u; } w;
                w.h[0] = (__bf16)p0; w.h[1] = (__bf16)p1;
                pk[m] = w.u;
            }
            swaplane32(pk[0], pk[2]); swaplane32(pk[1], pk[3]);
            swaplane32(pk[4], pk[6]); swaplane32(pk[5], pk[7]);
            union { unsigned u[4]; bf16_8 v; } pa0, pa1;
            pa0.u[0] = pk[0]; pa0.u[1] = pk[1]; pa0.u[2] = pk[2]; pa0.u[3] = pk[3];
            pa1.u[0] = pk[4]; pa1.u[1] = pk[5]; pa1.u[2] = pk[6]; pa1.u[3] = pk[7];

            o0 = MFMA32_BF(pa0.v, bv00, o0);
            o0 = MFMA32_BF(pa1.v, bv01, o0);
            o1 = MFMA32_BF(pa0.v, bv10, o1);
            o1 = MFMA32_BF(pa1.v, bv11, o1);
        }

        if (t + 1 < NT) {   // write-late into the other buffer
            const int nb = cur ^ 1;
            *(uint4*)&qt[nb][r][c0] = nq;
            *(uint4*)&vt[nb][r][c0] = nv;
        }
        __syncthreads();
    }

    float den = den2[0] + den2[1];
    den += __shfl_xor(den, 32);

    const size_t rowb = (size_t)b * NPOS + i0 + wv * 32;
    if (lane < 32)
        pden[(size_t)sblk * NROWS + rowb + lane] = den;

    #pragma unroll
    for (int reg = 0; reg < 16; ++reg) {
        int il = (reg & 3) + 8 * (reg >> 2) + 4 * g;
        size_t base = ((size_t)sblk * NROWS + rowb + il) * CMID + l31;
        po[base]      = (__bf16)o0[reg];
        po[base + 32] = (__bf16)o1[reg];
    }
}

// ---------------------------------------------------------------------------
// out_kernel (R15-proven v2): 64 rows per block (grid 512) — Wo
// register-preload amortized 4x. Scalar Wo loads are broadcast-friendly;
// R16's WoT 16B-stride loads regressed. Combine j-split partials
// (uint2-vectorized) -> at bf16 -> rowgroup-looped MFMA attn @ Wo ->
// fused BatchNorm -> direct stores. block 256.
// ---------------------------------------------------------------------------
__global__ __launch_bounds__(256) void out_kernel(
    const __bf16* __restrict__ po,      // [NSPLIT][32768][64]
    const float* __restrict__ pden,     // [NSPLIT][32768]
    const float* __restrict__ Wo,       // [64][256]
    const float* __restrict__ gamma, const float* __restrict__ beta,
    const float* __restrict__ mmean, const float* __restrict__ mvar,
    float* __restrict__ out)            // [32768][256]
{
    const int r0 = blockIdx.x * 64;
    const int t = threadIdx.x;
    const int lane = t & 63;
    const int wv = t >> 6;
    const int n0 = wv * 64;

    __shared__ __bf16 at[64][72];
    __shared__ float dinv[64];

    // Wo B-fragments from global (L2-hot), bf16 cast — issued early
    bf16_8 wb[4][2];
    #pragma unroll
    for (int nt = 0; nt < 4; ++nt) {
        int col = n0 + nt * 16 + (lane & 15);
        #pragma unroll
        for (int ch = 0; ch < 2; ++ch)
            #pragma unroll
            for (int e = 0; e < 8; ++e)
                wb[nt][ch][e] = (__bf16)Wo[(ch * 32 + (lane >> 4) * 8 + e) * OC + col];
    }

    // BN constants per owned column (4 cols/thread)
    float scs[4], shs[4];
    #pragma unroll
    for (int nt = 0; nt < 4; ++nt) {
        int col = n0 + nt * 16 + (lane & 15);
        scs[nt] = gamma[col] * rsqrtf(mvar[col] + 1e-3f);
        shs[nt] = beta[col] - mmean[col] * scs[nt];
    }

    if (t < 64) {
        float d = 0.f;
        #pragma unroll
        for (int s = 0; s < NSPLIT; ++s) d += pden[(size_t)s * NROWS + r0 + t];
        dinv[t] = 1.0f / d;
    }
    __syncthreads();

    // vectorized combine: 64x64 = 1024 quads, 4 per thread
    #pragma unroll
    for (int q = 0; q < 4; ++q) {
        int quad = t + q * 256;
        int rr = quad >> 4, c4 = (quad & 15) * 4;
        float s0 = 0.f, s1 = 0.f, s2 = 0.f, s3 = 0.f;
        #pragma unroll
        for (int s = 0; s < NSPLIT; ++s) {
            union { uint2 u; __bf16 h[4]; } qq;
            qq.u = *(const uint2*)&po[((size_t)s * NROWS + r0 + rr) * CMID + c4];
            s0 += (float)qq.h[0]; s1 += (float)qq.h[1];
            s2 += (float)qq.h[2]; s3 += (float)qq.h[3];
        }
        float di = dinv[rr];
        union { __bf16 h[4]; uint2 u; } o;
        o.h[0] = (__bf16)(s0 * di); o.h[1] = (__bf16)(s1 * di);
        o.h[2] = (__bf16)(s2 * di); o.h[3] = (__bf16)(s3 * di);
        *(uint2*)&at[rr][c4] = o.u;
    }
    __syncthreads();

    // rowgroup-looped MFMA: 4 groups of 16 rows; acc live range = 16 f32
    #pragma unroll
    for (int rg = 0; rg < 4; ++rg) {
        bf16_8 a0 = *(const bf16_8*)&at[rg * 16 + (lane & 15)][(lane >> 4) * 8];
        bf16_8 a1 = *(const bf16_8*)&at[rg * 16 + (lane & 15)][32 + (lane >> 4) * 8];
        #pragma unroll
        for (int nt = 0; nt < 4; ++nt) {
            int col = n0 + nt * 16 + (lane & 15);
            f32x4 acc = {0.f, 0.f, 0.f, 0.f};
            acc = MFMA_BF(a0, wb[nt][0], acc);
            acc = MFMA_BF(a1, wb[nt][1], acc);
            int rl = rg * 16 + (lane >> 4) * 4;
            #pragma unroll
            for (int rr = 0; rr < 4; ++rr)
                out[(size_t)(r0 + rl + rr) * OC + col] = acc[rr] * scs[nt] + shs[nt];
        }
    }
}

// ---------------------------------------------------------------------------
extern "C" void kernel_launch(void* const* d_in, const int* in_sizes, int n_in,
                              void* d_out, int out_size, void* d_ws, size_t ws_size,
                              hipStream_t stream) {
    const float* x     = (const float*)d_in[0];
    const float* Wk    = (const float*)d_in[1];
    const float* Wq    = (const float*)d_in[2];
    const float* Wv    = (const float*)d_in[3];
    const float* Wo    = (const float*)d_in[4];
    const float* gamma = (const float*)d_in[5];
    const float* beta  = (const float*)d_in[6];
    const float* mmean = (const float*)d_in[7];
    const float* mvar  = (const float*)d_in[8];
    float* out = (float*)d_out;

    // k/q/vT live in d_out (32 MiB): dead before out_kernel writes out.
    char* ob = (char*)d_out;
    const size_t MB4 = (size_t)NROWS * CMID * 2;   // 4 MiB
    _Float16* k_ws = (_Float16*)ob;                // 4 MiB
    _Float16* q_ws = (_Float16*)(ob + MB4);        // 4 MiB
    __bf16*   vT   = (__bf16*)(ob + 2 * MB4);      // 4 MiB

    __bf16* po   = (__bf16*)d_ws;                                 // 16 MiB
    float*  pden = (float*)((char*)d_ws + (size_t)NSPLIT * MB4);  // 512 KiB

    proj_kernel<<<512, 256, 0, stream>>>(x, Wk, Wq, Wv, k_ws, q_ws, vT);
    flash_kernel<<<dim3(16, 8, NSPLIT), 512, 0, stream>>>(k_ws, q_ws, vT, po, pden);
    out_kernel<<<512, 256, 0, stream>>>(po, pden, Wo, gamma, beta, mmean, mvar, out);
}

// Round 20
// 81.548 us; speedup vs baseline: 1.0915x; 1.0014x over previous
//
#include <hip/hip_runtime.h>
#include <hip/hip_bf16.h>

typedef __bf16 bf16_8 __attribute__((ext_vector_type(8)));
typedef _Float16 f16x8 __attribute__((ext_vector_type(8)));
typedef float f32x2 __attribute__((ext_vector_type(2)));
typedef float f32x4 __attribute__((ext_vector_type(4)));
typedef float f32x16 __attribute__((ext_vector_type(16)));

#define MFMA_BF(A, B, C)    __builtin_amdgcn_mfma_f32_16x16x32_bf16(A, B, C, 0, 0, 0)
#define MFMA_F16(A, B, C)   __builtin_amdgcn_mfma_f32_16x16x32_f16(A, B, C, 0, 0, 0)
#define MFMA32_F16(A, B, C) __builtin_amdgcn_mfma_f32_32x32x16_f16(A, B, C, 0, 0, 0)
#define MFMA32_BF(A, B, C)  __builtin_amdgcn_mfma_f32_32x32x16_bf16(A, B, C, 0, 0, 0)

#define BATCH 8
#define NPOS 4096            // 64*64 spatial
#define CIN 256
#define CMID 64
#define OC 256
#define NROWS (BATCH * NPOS) // 32768
#define NSPLIT 4             // j-split (nsplit=8 regressed: reg cap is 16 waves/CU)
#define LOG2E 1.44269504088896f

// lane i <-> lane i+32 register swap (hi half of a <-> lo half of b)
__device__ inline void swaplane32(unsigned& a, unsigned& b) {
    asm volatile("v_permlane32_swap_b32 %0, %1" : "+v"(a), "+v"(b));
}

// single-instruction 2^x. R11 LESSON: bare inline-asm v_exp_f32 is WRONG —
// trans-op forwarding hazard invisible to the compiler. Builtin is safe.
#if __has_builtin(__builtin_amdgcn_exp2f)
__device__ inline float fexp2(float x) { return __builtin_amdgcn_exp2f(x); }
#else
__device__ inline float fexp2(float x) {
    float r;
    asm("v_exp_f32 %0, %1\n\ts_nop 1" : "=v"(r) : "v"(x));  // nop INSIDE blob
    return r;
}
#endif

// ---------------------------------------------------------------------------
// proj_kernel (fused-m, R18-proven): k,q,v = x @ {Wk,Wq,Wv} with x read ONCE
// (grid 512). One 34 KB fp16 W buffer (4 blocks/CU), float4 conflict-free
// staging, 1x MFMA per m. k,q accumulators in VGPRs across the m-loop;
// repacked into disjoint halves of the reused wt buffer.
// Wk pre-scaled by log2e so flash uses exp2 directly.
// ---------------------------------------------------------------------------
__global__ __launch_bounds__(256) void proj_kernel(
    const float* __restrict__ x,
    const float* __restrict__ Wk, const float* __restrict__ Wq,
    const float* __restrict__ Wv,
    _Float16* __restrict__ k_ws, _Float16* __restrict__ q_ws,
    __bf16* __restrict__ vT_ws)
{
    const int r0 = blockIdx.x * 64;

    __shared__ _Float16 wt[64][266];   // W^T [col][k]; later reused as repack

    const int lane = threadIdx.x & 63;
    const int wv = threadIdx.x >> 6;
    const int kbase = ((lane >> 4) & 3) * 8;
    const int arow = r0 + wv * 16 + (lane & 15);
    const float* xrow = x + (size_t)arow * CIN;

    // x tile -> fp16 registers, ONCE
    f16x8 a[8];
    #pragma unroll
    for (int kk = 0; kk < 8; ++kk) {
        const float4* xp = (const float4*)(xrow + kk * 32 + kbase);
        float4 x0 = xp[0], x1 = xp[1];
        float xs[8] = {x0.x, x0.y, x0.z, x0.w, x1.x, x1.y, x1.z, x1.w};
        #pragma unroll
        for (int e = 0; e < 8; ++e) a[kk][e] = (_Float16)xs[e];
    }

    const float* Ws[3] = {Wk, Wq, Wv};
    f32x4 acck[4], accq[4];
    const int rloc = wv * 16 + ((lane >> 4) & 3) * 4;

    #pragma unroll
    for (int m = 0; m < 3; ++m) {
        if (m) __syncthreads();            // previous phase's wt reads done
        const float wscale = (m == 0) ? LOG2E : 1.0f;
        for (int idx = threadIdx.x; idx < 64 * 64; idx += 256) {
            int c4 = (idx & 15) * 4, k = idx >> 4;
            float4 w4 = *(const float4*)&Ws[m][k * 64 + c4];
            wt[c4 + 0][k] = (_Float16)(w4.x * wscale);
            wt[c4 + 1][k] = (_Float16)(w4.y * wscale);
            wt[c4 + 2][k] = (_Float16)(w4.z * wscale);
            wt[c4 + 3][k] = (_Float16)(w4.w * wscale);
        }
        __syncthreads();

        f32x4 acc[4] = {f32x4{0,0,0,0}, f32x4{0,0,0,0}, f32x4{0,0,0,0}, f32x4{0,0,0,0}};
        #pragma unroll
        for (int kk = 0; kk < 8; ++kk) {
            #pragma unroll
            for (int nt = 0; nt < 4; ++nt) {
                f16x8 b = *(const f16x8*)&wt[(lane & 15) + 16 * nt][kk * 32 + kbase];
                acc[nt] = MFMA_F16(a[kk], b, acc[nt]);
            }
        }

        if (m == 0) {
            #pragma unroll
            for (int nt = 0; nt < 4; ++nt) acck[nt] = acc[nt];
        } else if (m == 1) {
            #pragma unroll
            for (int nt = 0; nt < 4; ++nt) accq[nt] = acc[nt];
        } else {
            const int rrow = r0 + rloc;
            const int b = rrow >> 12;
            const int n = rrow & (NPOS - 1);
            #pragma unroll
            for (int nt = 0; nt < 4; ++nt) {
                int cv = (lane & 15) + 16 * nt;
                union { __bf16 h[4]; uint2 u; } pk;
                #pragma unroll
                for (int r = 0; r < 4; ++r) pk.h[r] = (__bf16)acc[nt][r];
                *(uint2*)(vT_ws + ((size_t)b * CMID + cv) * NPOS + n) = pk.u;
            }
        }
    }

    // repack k,q into disjoint halves of wt (viewed flat as 2x [64][72])
    __syncthreads();                       // all m=2 wt reads done
    _Float16* rpk = &wt[0][0];
    _Float16* rpq = rpk + 64 * 72;
    #pragma unroll
    for (int nt = 0; nt < 4; ++nt)
        #pragma unroll
        for (int r = 0; r < 4; ++r) {
            int off = (rloc + r) * 72 + (lane & 15) + 16 * nt;
            rpk[off] = (_Float16)acck[nt][r];
            rpq[off] = (_Float16)accq[nt][r];
        }
    __syncthreads();
    const int row = threadIdx.x >> 3, c0 = (threadIdx.x & 7) * 8;
    #pragma unroll
    for (int h = 0; h < 2; ++h) {
        uint4 vk = *(const uint4*)&rpk[(row + 32 * h) * 72 + c0];
        *(uint4*)(k_ws + (size_t)(r0 + row + 32 * h) * CMID + c0) = vk;
        uint4 vq = *(const uint4*)&rpq[(row + 32 * h) * 72 + c0];
        *(uint4*)(q_ws + (size_t)(r0 + row + 32 * h) * CMID + c0) = vq;
    }
}

// ---------------------------------------------------------------------------
// flash_kernel: R12 structure + f32x2 den (R19-proven, 45.2 us). Streaming
// attention, 32x32 swapped-QK^T, in-register P, 8 waves x 32 i-rows
// (block=512), double-buffered tiles, issue-early/write-late staging.
// (den-MFMA, setprio, nsplit=8, i=64/wave all regressed — R7/R10/R13.)
// grid (16, 8, NSPLIT).
// ---------------------------------------------------------------------------
__global__ __launch_bounds__(512, 4) void flash_kernel(
    const _Float16* __restrict__ k_ws,  // [32768][64]
    const _Float16* __restrict__ q_ws,  // [32768][64]
    const __bf16* __restrict__ vT_ws,   // [8][64][4096]
    __bf16* __restrict__ po,            // [NSPLIT][32768][64]
    float* __restrict__ pden)           // [NSPLIT][32768]
{
    const int b = blockIdx.y;
    const int i0 = blockIdx.x * 256;
    const int sblk = blockIdx.z;
    const int jbase = sblk * (NPOS / NSPLIT);
    const int lane = threadIdx.x & 63;
    const int wv = threadIdx.x >> 6;    // 0..7
    const int l31 = lane & 31;
    const int g = lane >> 5;

    __shared__ _Float16 qt[2][64][72];
    __shared__ __bf16 vt[2][64][72];

    // wave's 32 k-rows as B-fragments
    f16x8 kf[4];
    {
        const _Float16* kp =
            k_ws + ((size_t)(b * NPOS + i0 + wv * 32 + l31)) * CMID + g * 8;
        #pragma unroll
        for (int c = 0; c < 4; ++c) kf[c] = *(const f16x8*)(kp + c * 16);
    }

    f32x16 o0 = {0,0,0,0,0,0,0,0,0,0,0,0,0,0,0,0};
    f32x16 o1 = {0,0,0,0,0,0,0,0,0,0,0,0,0,0,0,0};
    f32x2 den2 = {0.f, 0.f};

    // staging map: 512 threads x 16B = one 64x64 fp16/bf16 tile
    const int r = threadIdx.x >> 3, c0 = (threadIdx.x & 7) * 8;
    uint4 nq, nv;

    // prologue: tile 0
    {
        nq = *(const uint4*)(q_ws + ((size_t)(b * NPOS + jbase + r)) * CMID + c0);
        nv = *(const uint4*)(vT_ws + ((size_t)b * CMID + r) * NPOS + jbase + c0);
        *(uint4*)&qt[0][r][c0] = nq;
        *(uint4*)&vt[0][r][c0] = nv;
    }
    __syncthreads();

    const int NT = (NPOS / NSPLIT) / 64;  // 16
    for (int t = 0; t < NT; ++t) {
        const int cur = t & 1;
        if (t + 1 < NT) {   // issue next-tile loads early
            int j1 = jbase + (t + 1) * 64;
            nq = *(const uint4*)(q_ws + ((size_t)(b * NPOS + j1 + r)) * CMID + c0);
            nv = *(const uint4*)(vT_ws + ((size_t)b * CMID + r) * NPOS + j1 + c0);
        }

        #pragma unroll
        for (int jj = 0; jj < 2; ++jj) {
            f16x8 aq[4];
            #pragma unroll
            for (int c = 0; c < 4; ++c)
                aq[c] = *(const f16x8*)&qt[cur][jj * 32 + l31][c * 16 + g * 8];
            bf16_8 bv00 = *(const bf16_8*)&vt[cur][l31][jj * 32 + g * 8];
            bf16_8 bv01 = *(const bf16_8*)&vt[cur][l31][jj * 32 + 16 + g * 8];
            bf16_8 bv10 = *(const bf16_8*)&vt[cur][32 + l31][jj * 32 + g * 8];
            bf16_8 bv11 = *(const bf16_8*)&vt[cur][32 + l31][jj * 32 + 16 + g * 8];

            f32x16 s = {0,0,0,0,0,0,0,0,0,0,0,0,0,0,0,0};
            s = MFMA32_F16(aq[0], kf[0], s);
            s = MFMA32_F16(aq[1], kf[1], s);
            s = MFMA32_F16(aq[2], kf[2], s);
            s = MFMA32_F16(aq[3], kf[3], s);

            unsigned pk[8];
            #pragma unroll
            for (int m = 0; m < 8; ++m) {
                float p0 = fexp2(s[2 * m]);
                float p1 = fexp2(s[2 * m + 1]);
                den2 += (f32x2){p0, p1};
                union { __bf16 h[2]; unsigned u; } w;
                w.h[0] = (__bf16)p0; w.h[1] = (__bf16)p1;
                pk[m] = w.u;
            }
            swaplane32(pk[0], pk[2]); swaplane32(pk[1], pk[3]);
            swaplane32(pk[4], pk[6]); swaplane32(pk[5], pk[7]);
            union { unsigned u[4]; bf16_8 v; } pa0, pa1;
            pa0.u[0] = pk[0]; pa0.u[1] = pk[1]; pa0.u[2] = pk[2]; pa0.u[3] = pk[3];
            pa1.u[0] = pk[4]; pa1.u[1] = pk[5]; pa1.u[2] = pk[6]; pa1.u[3] = pk[7];

            o0 = MFMA32_BF(pa0.v, bv00, o0);
            o0 = MFMA32_BF(pa1.v, bv01, o0);
            o1 = MFMA32_BF(pa0.v, bv10, o1);
            o1 = MFMA32_BF(pa1.v, bv11, o1);
        }

        if (t + 1 < NT) {   // write-late into the other buffer
            const int nb = cur ^ 1;
            *(uint4*)&qt[nb][r][c0] = nq;
            *(uint4*)&vt[nb][r][c0] = nv;
        }
        __syncthreads();
    }

    float den = den2[0] + den2[1];
    den += __shfl_xor(den, 32);

    const size_t rowb = (size_t)b * NPOS + i0 + wv * 32;
    if (lane < 32)
        pden[(size_t)sblk * NROWS + rowb + lane] = den;

    #pragma unroll
    for (int reg = 0; reg < 16; ++reg) {
        int il = (reg & 3) + 8 * (reg >> 2) + 4 * g;
        size_t base = ((size_t)sblk * NROWS + rowb + il) * CMID + l31;
        po[base]      = (__bf16)o0[reg];
        po[base + 32] = (__bf16)o1[reg];
    }
}

// ---------------------------------------------------------------------------
// out_kernel (R15 structure + uint4 combine): 64 rows per block (grid 512).
// Wo scalar loads broadcast-friendly (R16's WoT 16B-stride regressed).
// Combine j-split partials with uint4 (8 bf16) granularity — half the load
// instructions of the uint2 version at identical bytes/coalescing ->
// at bf16 -> rowgroup-looped MFMA attn @ Wo -> fused BatchNorm -> direct
// stores. block 256 (4 waves, wave wv owns cols wv*64..+63).
// ---------------------------------------------------------------------------
__global__ __launch_bounds__(256) void out_kernel(
    const __bf16* __restrict__ po,      // [NSPLIT][32768][64]
    const float* __restrict__ pden,     // [NSPLIT][32768]
    const float* __restrict__ Wo,       // [64][256]
    const float* __restrict__ gamma, const float* __restrict__ beta,
    const float* __restrict__ mmean, const float* __restrict__ mvar,
    float* __restrict__ out)            // [32768][256]
{
    const int r0 = blockIdx.x * 64;
    const int t = threadIdx.x;
    const int lane = t & 63;
    const int wv = t >> 6;
    const int n0 = wv * 64;

    __shared__ __bf16 at[64][72];
    __shared__ float dinv[64];

    // Wo B-fragments from global (L2-hot), bf16 cast — issued early
    bf16_8 wb[4][2];
    #pragma unroll
    for (int nt = 0; nt < 4; ++nt) {
        int col = n0 + nt * 16 + (lane & 15);
        #pragma unroll
        for (int ch = 0; ch < 2; ++ch)
            #pragma unroll
            for (int e = 0; e < 8; ++e)
                wb[nt][ch][e] = (__bf16)Wo[(ch * 32 + (lane >> 4) * 8 + e) * OC + col];
    }

    // BN constants per owned column (4 cols/thread)
    float scs[4], shs[4];
    #pragma unroll
    for (int nt = 0; nt < 4; ++nt) {
        int col = n0 + nt * 16 + (lane & 15);
        scs[nt] = gamma[col] * rsqrtf(mvar[col] + 1e-3f);
        shs[nt] = beta[col] - mmean[col] * scs[nt];
    }

    if (t < 64) {
        float d = 0.f;
        #pragma unroll
        for (int s = 0; s < NSPLIT; ++s) d += pden[(size_t)s * NROWS + r0 + t];
        dinv[t] = 1.0f / d;
    }
    __syncthreads();

    // vectorized combine: 64x64 elements = 512 octets (8 bf16), 2 per thread
    #pragma unroll
    for (int q = 0; q < 2; ++q) {
        int oct = t + q * 256;
        int rr = oct >> 3, c8 = (oct & 7) * 8;
        float sum[8] = {0.f, 0.f, 0.f, 0.f, 0.f, 0.f, 0.f, 0.f};
        #pragma unroll
        for (int s = 0; s < NSPLIT; ++s) {
            union { uint4 u; __bf16 h[8]; } qq;
            qq.u = *(const uint4*)&po[((size_t)s * NROWS + r0 + rr) * CMID + c8];
            #pragma unroll
            for (int e = 0; e < 8; ++e) sum[e] += (float)qq.h[e];
        }
        float di = dinv[rr];
        union { __bf16 h[8]; uint4 u; } o;
        #pragma unroll
        for (int e = 0; e < 8; ++e) o.h[e] = (__bf16)(sum[e] * di);
        *(uint4*)&at[rr][c8] = o.u;
    }
    __syncthreads();

    // rowgroup-looped MFMA: 4 groups of 16 rows; acc live range = 16 f32
    #pragma unroll
    for (int rg = 0; rg < 4; ++rg) {
        bf16_8 a0 = *(const bf16_8*)&at[rg * 16 + (lane & 15)][(lane >> 4) * 8];
        bf16_8 a1 = *(const bf16_8*)&at[rg * 16 + (lane & 15)][32 + (lane >> 4) * 8];
        #pragma unroll
        for (int nt = 0; nt < 4; ++nt) {
            int col = n0 + nt * 16 + (lane & 15);
            f32x4 acc = {0.f, 0.f, 0.f, 0.f};
            acc = MFMA_BF(a0, wb[nt][0], acc);
            acc = MFMA_BF(a1, wb[nt][1], acc);
            int rl = rg * 16 + (lane >> 4) * 4;
            #pragma unroll
            for (int rr = 0; rr < 4; ++rr)
                out[(size_t)(r0 + rl + rr) * OC + col] = acc[rr] * scs[nt] + shs[nt];
        }
    }
}

// ---------------------------------------------------------------------------
extern "C" void kernel_launch(void* const* d_in, const int* in_sizes, int n_in,
                              void* d_out, int out_size, void* d_ws, size_t ws_size,
                              hipStream_t stream) {
    const float* x     = (const float*)d_in[0];
    const float* Wk    = (const float*)d_in[1];
    const float* Wq    = (const float*)d_in[2];
    const float* Wv    = (const float*)d_in[3];
    const float* Wo    = (const float*)d_in[4];
    const float* gamma = (const float*)d_in[5];
    const float* beta  = (const float*)d_in[6];
    const float* mmean = (const float*)d_in[7];
    const float* mvar  = (const float*)d_in[8];
    float* out = (float*)d_out;

    // k/q/vT live in d_out (32 MiB): dead before out_kernel writes out.
    char* ob = (char*)d_out;
    const size_t MB4 = (size_t)NROWS * CMID * 2;   // 4 MiB
    _Float16* k_ws = (_Float16*)ob;                // 4 MiB
    _Float16* q_ws = (_Float16*)(ob + MB4);        // 4 MiB
    __bf16*   vT   = (__bf16*)(ob + 2 * MB4);      // 4 MiB

    __bf16* po   = (__bf16*)d_ws;                                 // 16 MiB
    float*  pden = (float*)((char*)d_ws + (size_t)NSPLIT * MB4);  // 512 KiB

    proj_kernel<<<512, 256, 0, stream>>>(x, Wk, Wq, Wv, k_ws, q_ws, vT);
    flash_kernel<<<dim3(16, 8, NSPLIT), 512, 0, stream>>>(k_ws, q_ws, vT, po, pden);
    out_kernel<<<512, 256, 0, stream>>>(po, pden, Wo, gamma, beta, mmean, mvar, out);
}